// Round 11
// baseline (1102.501 us; speedup 1.0000x reference)
//
#include <hip/hip_runtime.h>
#include <hip/hip_cooperative_groups.h>

namespace cg = cooperative_groups;

constexpr int CB   = 16;    // batch
constexpr int CN   = 512;   // nodes
constexpr int CD   = 256;   // dim
constexpr int CPH  = 8;     // pgat heads
constexpr int CDH  = 32;    // CD / CPH
constexpr int CNP1 = 513;   // nodes + c_node
constexpr int CFH  = 128;
constexpr int CNC  = 2;

typedef __bf16 bf16x8 __attribute__((ext_vector_type(8)));
typedef __bf16 bf16x4 __attribute__((ext_vector_type(4)));
typedef float  f32x4  __attribute__((ext_vector_type(4)));

__device__ __forceinline__ float tanh_fast(float x) {
  x = fminf(fmaxf(x, -15.f), 15.f);
  float e = __expf(2.f * x);
  return (e - 1.f) / (e + 1.f);
}

__device__ __forceinline__ float exp2x_clamped(float x) {
  x = fminf(fmaxf(x, -18.f), 18.f);
  return __expf(2.f * x);
}

struct Params {
  const float* pmask; const float* feature; const float* cnode;
  const float* pgat_W; const float* pgat_att;
  const float* upw[24];                       // [up*6 + j]
  const float* ugat_W; const float* ugat_att;
  const float* mlp_w1; const float* mlp_b1;
  const float* mlp_w2; const float* mlp_b2;
  const float* fcf[8];
  float* out;
  float* qk;      // bf16 storage
  float* feat1; float* comb;
  float* sq; float* sk;
  float* qt; float* qkb; float* den; float* head;
  float* u; float* uqk; float* sqk; float* weff;
};

// ---- per-phase LDS overlays (union via char buffer) ----
struct GemmS { __bf16 aHi[64][56], aLo[64][56], bHi[64][56], bLo[64][56]; };
struct AuxS  { float cl[CD], ql[CD], red[256]; };
struct AttnS { __bf16 vslice[32][520]; float skl[CN], ckm[CN], sql64[64]; };
struct HeadS { float qtl[4][CD]; float qkbl[4]; float attl[4][64]; };
struct OutS  { float hl[CD], xl[CD], qkl[CD]; };
struct MlpS  { float uq[4][CD]; float sl[4][4], kl[4][4]; float xl[CD], h1[CFH], h2[CFH]; };

// ---------- R3-verified staged gemm tile (x: n-tile 0..3, y: m-tile 0..127)
__device__ __forceinline__ void gemm_tile(
    const float* __restrict__ A, const float* __restrict__ W,
    const float* __restrict__ attnw, __bf16* __restrict__ C,
    float* __restrict__ sqT, float* __restrict__ skT,
    int x, int y, int t, char* smem)
{
  GemmS& S = *reinterpret_cast<GemmS*>(smem);
  const int nt = x * 64, mt = y * 64;
  const int wv = t >> 6, ln = t & 63;
  const int quad = ln >> 4, lc = ln & 15;

  f32x4 acc[4];
#pragma unroll
  for (int j = 0; j < 4; j++)
#pragma unroll
    for (int r = 0; r < 4; r++) acc[j][r] = 0.f;

  const int sr  = t >> 2;
  const int skq = (t & 3) * 8;

  for (int k0 = 0; k0 < 256; k0 += 32) {
    __syncthreads();
    {
      const float* ap = A + (size_t)(mt + sr) * 256 + k0 + skq;
      const float* wp = W + (size_t)(nt + sr) * 256 + k0 + skq;
      float4 a0 = *(const float4*)ap, a1 = *(const float4*)(ap + 4);
      float4 w0 = *(const float4*)wp, w1 = *(const float4*)(wp + 4);
      float av[8] = {a0.x, a0.y, a0.z, a0.w, a1.x, a1.y, a1.z, a1.w};
      float wvv[8] = {w0.x, w0.y, w0.z, w0.w, w1.x, w1.y, w1.z, w1.w};
      bf16x8 ah, al, bh, bl;
#pragma unroll
      for (int j = 0; j < 8; j++) {
        ah[j] = (__bf16)av[j];
        al[j] = (__bf16)(av[j] - (float)ah[j]);
        bh[j] = (__bf16)wvv[j];
        bl[j] = (__bf16)(wvv[j] - (float)bh[j]);
      }
      *(bf16x8*)&S.aHi[sr][skq] = ah;
      *(bf16x8*)&S.aLo[sr][skq] = al;
      *(bf16x8*)&S.bHi[sr][skq] = bh;
      *(bf16x8*)&S.bLo[sr][skq] = bl;
    }
    __syncthreads();
    bf16x8 fah = *(const bf16x8*)&S.aHi[wv * 16 + lc][quad * 8];
    bf16x8 fal = *(const bf16x8*)&S.aLo[wv * 16 + lc][quad * 8];
#pragma unroll
    for (int j = 0; j < 4; j++) {
      bf16x8 fbh = *(const bf16x8*)&S.bHi[j * 16 + lc][quad * 8];
      bf16x8 fbl = *(const bf16x8*)&S.bLo[j * 16 + lc][quad * 8];
      acc[j] = __builtin_amdgcn_mfma_f32_16x16x32_bf16(fah, fbh, acc[j], 0, 0, 0);
      acc[j] = __builtin_amdgcn_mfma_f32_16x16x32_bf16(fah, fbl, acc[j], 0, 0, 0);
      acc[j] = __builtin_amdgcn_mfma_f32_16x16x32_bf16(fal, fbh, acc[j], 0, 0, 0);
    }
  }
#pragma unroll
  for (int j = 0; j < 4; j++)
#pragma unroll
    for (int r = 0; r < 4; r++)
      C[(size_t)(mt + wv * 16 + quad * 4 + r) * 256 + nt + j * 16 + lc] =
          (__bf16)acc[j][r];

  const int hA = x * 2, hB = hA + 1;
  const float wqa0 = attnw[hA * 64 + lc],      wqa1 = attnw[hA * 64 + 16 + lc];
  const float wka0 = attnw[hA * 64 + 32 + lc], wka1 = attnw[hA * 64 + 48 + lc];
  const float wqb0 = attnw[hB * 64 + lc],      wqb1 = attnw[hB * 64 + 16 + lc];
  const float wkb0 = attnw[hB * 64 + 32 + lc], wkb1 = attnw[hB * 64 + 48 + lc];
  float sqa[4], ska[4], sqb[4], skb[4];
#pragma unroll
  for (int r = 0; r < 4; r++) {
    sqa[r] = acc[0][r] * wqa0 + acc[1][r] * wqa1;
    ska[r] = acc[0][r] * wka0 + acc[1][r] * wka1;
    sqb[r] = acc[2][r] * wqb0 + acc[3][r] * wqb1;
    skb[r] = acc[2][r] * wkb0 + acc[3][r] * wkb1;
  }
#pragma unroll
  for (int m = 1; m <= 8; m <<= 1) {
#pragma unroll
    for (int r = 0; r < 4; r++) {
      sqa[r] += __shfl_xor(sqa[r], m);
      ska[r] += __shfl_xor(ska[r], m);
      sqb[r] += __shfl_xor(sqb[r], m);
      skb[r] += __shfl_xor(skb[r], m);
    }
  }
  if (lc == 0) {
#pragma unroll
    for (int r = 0; r < 4; r++) {
      int gm = mt + wv * 16 + quad * 4 + r;
      int bb = gm >> 9, nn = gm & 511;
      sqT[((size_t)bb * CPH + hA) * CN + nn] = sqa[r];
      skT[((size_t)bb * CPH + hA) * CN + nn] = ska[r];
      sqT[((size_t)bb * CPH + hB) * CN + nn] = sqb[r];
      skT[((size_t)bb * CPH + hB) * CN + nn] = skb[r];
    }
  }
}

// ---------- R6-verified aux (up_q_all body)
__device__ __forceinline__ void up_q_aux(const Params& p, int up, int b, int t, char* smem)
{
  AuxS& S = *reinterpret_cast<AuxS*>(smem);
  const float* qw = p.upw[up * 6 + 0];
  const float* qb = p.upw[up * 6 + 1];
  const float* kw = p.upw[up * 6 + 2];
  const float* kb = p.upw[up * 6 + 3];
  const float* ow = p.upw[up * 6 + 4];
  S.cl[t] = p.cnode[b * CD + t];
  p.head[((size_t)b * 4 + up) * CD + t] = 0.f;
  if (t == 0) p.den[b * 4 + up] = 0.f;
  {
#pragma unroll
    for (int i = 0; i < 4; i++) {
      int idx = t + 256 * i;               // 0..1023
      int n = b * 16 + (idx >> 6), e4 = (idx & 63) * 4;
      const float* base = ow + (size_t)n * (4 * CD) + e4;
      float4 w0 = *(const float4*)(base);
      float4 w1 = *(const float4*)(base + CD);
      float4 w2 = *(const float4*)(base + 2 * CD);
      float4 w3 = *(const float4*)(base + 3 * CD);
      float4 o;
      o.x = w0.x + w1.x + w2.x + w3.x;
      o.y = w0.y + w1.y + w2.y + w3.y;
      o.z = w0.z + w1.z + w2.z + w3.z;
      o.w = w0.w + w1.w + w2.w + w3.w;
      *(float4*)(p.weff + (size_t)up * CD * CD + (size_t)n * CD + e4) = o;
    }
  }
  __syncthreads();
  if (up == 0) p.comb[((size_t)b * CNP1 + CN) * CD + t] = S.cl[t];
  {
    const float* wr = qw + (size_t)t * CD;
    float a = qb[t];
#pragma unroll 4
    for (int k = 0; k < CD; k += 4) {
      float4 w4 = *(const float4*)(wr + k);
      a += S.cl[k] * w4.x + S.cl[k + 1] * w4.y + S.cl[k + 2] * w4.z + S.cl[k + 3] * w4.w;
    }
    S.ql[t] = a;
  }
  __syncthreads();
  {
    float a0 = 0.f, a1 = 0.f, a2 = 0.f, a3 = 0.f;
#pragma unroll 4
    for (int d = 0; d < CD; d += 4) {
      a0 += S.ql[d]     * kw[(d)     * CD + t];
      a1 += S.ql[d + 1] * kw[(d + 1) * CD + t];
      a2 += S.ql[d + 2] * kw[(d + 2) * CD + t];
      a3 += S.ql[d + 3] * kw[(d + 3) * CD + t];
    }
    p.qt[((size_t)up * CB + b) * CD + t] = (a0 + a1) + (a2 + a3);
  }
  S.red[t] = S.ql[t] * kb[t];
  __syncthreads();
  for (int s = 128; s > 0; s >>= 1) { if (t < s) S.red[t] += S.red[t + s]; __syncthreads(); }
  if (t == 0) p.qkb[up * CB + b] = S.red[0];
}

// ---------- R8-verified barrier-free attention tile
__device__ __forceinline__ void attn_tile(
    const __bf16* __restrict__ qk, const float* __restrict__ sqT,
    const float* __restrict__ skT, const float* __restrict__ pmask,
    const float* __restrict__ fin, float* __restrict__ fout, int outStride,
    int qt, int h, int b, int t, char* smem)
{
  AttnS& S = *reinterpret_cast<AttnS*>(smem);
  const int wv = t >> 6, ln = t & 63;
  const int quad = ln >> 4, lc = ln & 15;

  for (int i = t; i < CN; i += 256) {
    S.skl[i] = exp2x_clamped(skT[((size_t)b * CPH + h) * CN + i]);
    S.ckm[i] = (pmask[b * CN + i] == 0.f) ? 0.f : 1.f;
  }
  if (t < 64) S.sql64[t] = exp2x_clamped(sqT[((size_t)b * CPH + h) * CN + qt * 64 + t]);
  for (int i = t; i < CN * 4; i += 256) {
    const int k = i >> 2, dq = (i & 3) * 8;
    bf16x8 v = *(const bf16x8*)(qk + ((size_t)(b * CN + k)) * CD + h * CDH + dq);
#pragma unroll
    for (int j = 0; j < 8; j++) S.vslice[dq + j][k] = v[j];
  }
  __syncthreads();

  const int q0 = qt * 64 + wv * 16;
  const float tq = S.sql64[wv * 16 + lc];
  const float qf = S.ckm[q0 + lc];

  f32x4 V0 = {0.f,0.f,0.f,0.f}, V1 = {0.f,0.f,0.f,0.f}, Dn = {0.f,0.f,0.f,0.f};
  bf16x8 ones;
#pragma unroll
  for (int j = 0; j < 8; j++) ones[j] = (__bf16)1.0f;

#pragma unroll 2
  for (int k0 = 0; k0 < CN; k0 += 32) {
    bf16x8 fa;
#pragma unroll
    for (int j = 0; j < 8; j++) {
      const int kk = k0 + quad * 8 + j;
      float u  = tq * S.skl[kk];
      float th = (u - 1.f) * __builtin_amdgcn_rcpf(u + 1.f);
      th *= qf * S.ckm[kk];
      fa[j] = (__bf16)__expf(th);
    }
    bf16x8 b0 = *(const bf16x8*)&S.vslice[lc][k0 + quad * 8];
    bf16x8 b1 = *(const bf16x8*)&S.vslice[16 + lc][k0 + quad * 8];
    V0 = __builtin_amdgcn_mfma_f32_16x16x32_bf16(fa, b0, V0, 0, 0, 0);
    V1 = __builtin_amdgcn_mfma_f32_16x16x32_bf16(fa, b1, V1, 0, 0, 0);
    Dn = __builtin_amdgcn_mfma_f32_16x16x32_bf16(fa, ones, Dn, 0, 0, 0);
  }

  const int d0 = h * CDH + lc;
#pragma unroll
  for (int r = 0; r < 4; r++) {
    const int q = q0 + quad * 4 + r;
    float inv = 1.f / Dn[r];
    const float* ip = fin + ((size_t)b * CN + q) * CD;
    float*       op = fout + ((size_t)b * outStride + q) * CD;
    op[d0]      = ip[d0]      + tanh_fast(V0[r] * inv);
    op[d0 + 16] = ip[d0 + 16] + tanh_fast(V1[r] * inv);
  }
}

// ---------- R8-verified headsim block
__device__ __forceinline__ void headsim_blk(const Params& p, int b, int n0, int t, char* smem)
{
  HeadS& S = *reinterpret_cast<HeadS*>(smem);
  const int up = t >> 6, j = t & 63;
  for (int i = t; i < 4 * CD; i += 256)
    S.qtl[i >> 8][i & 255] = p.qt[((size_t)(i >> 8) * CB + b) * CD + (i & 255)];
  if (t < 4) S.qkbl[t] = p.qkb[t * CB + b];
  __syncthreads();
  {
    const int n = n0 + j;
    float e = 0.f;
    if (n < CNP1) {
      const float* cr = p.comb + ((size_t)b * CNP1 + n) * CD;
      float pp = 0.f;
#pragma unroll 4
      for (int d = 0; d < CD; d += 4) {
        float4 c4 = *(const float4*)(cr + d);
        pp += S.qtl[up][d] * c4.x + S.qtl[up][d + 1] * c4.y
            + S.qtl[up][d + 2] * c4.z + S.qtl[up][d + 3] * c4.w;
      }
      float s = (pp + S.qkbl[up]) * 0.0625f;
      float m = (n < CN) ? p.pmask[b * CN + n] : 1.f;
      if (m == 0.f) s = 1e-8f;
      e = __expf(s);
    }
    S.attl[up][j] = e;
  }
  __syncthreads();
  float4 acc = make_float4(0.f, 0.f, 0.f, 0.f);
  const int nmax = min(64, CNP1 - n0);
  for (int jj = 0; jj < nmax; jj++) {
    float a = S.attl[up][jj];
    float4 c4 = *(const float4*)(p.comb + ((size_t)b * CNP1 + n0 + jj) * CD + j * 4);
    acc.x += a * c4.x; acc.y += a * c4.y; acc.z += a * c4.z; acc.w += a * c4.w;
  }
  float* hp = p.head + ((size_t)b * 4 + up) * CD + j * 4;
  atomicAdd(hp + 0, acc.x); atomicAdd(hp + 1, acc.y);
  atomicAdd(hp + 2, acc.z); atomicAdd(hp + 3, acc.w);
  if (j == 0) {
    float s = 0.f;
    for (int jj = 0; jj < 64; jj++) s += S.attl[up][jj];
    atomicAdd(p.den + b * 4 + up, s);
  }
}

// ---------- R8-verified up_out + ugat projection block
__device__ __forceinline__ void out_ugat_blk(const Params& p, int b, int up, int t, char* smem)
{
  OutS& S = *reinterpret_cast<OutS*>(smem);
  const float* ob = p.upw[up * 6 + 5];
  S.hl[t] = p.head[((size_t)b * 4 + up) * CD + t] * (1.f / p.den[b * 4 + up]);
  __syncthreads();
  {
    const float* r0 = p.weff + (size_t)up * CD * CD + (size_t)t * CD;
    float p0 = 0.f, p1 = 0.f, p2 = 0.f, p3 = 0.f;
#pragma unroll 4
    for (int d = 0; d < CD; d += 16) {
      float4 w0 = *(const float4*)(r0 + d);
      float4 w1 = *(const float4*)(r0 + d + 4);
      float4 w2 = *(const float4*)(r0 + d + 8);
      float4 w3 = *(const float4*)(r0 + d + 12);
      p0 += S.hl[d +  0] * w0.x + S.hl[d +  1] * w0.y + S.hl[d +  2] * w0.z + S.hl[d +  3] * w0.w;
      p1 += S.hl[d +  4] * w1.x + S.hl[d +  5] * w1.y + S.hl[d +  6] * w1.z + S.hl[d +  7] * w1.w;
      p2 += S.hl[d +  8] * w2.x + S.hl[d +  9] * w2.y + S.hl[d + 10] * w2.z + S.hl[d + 11] * w2.w;
      p3 += S.hl[d + 12] * w3.x + S.hl[d + 13] * w3.y + S.hl[d + 14] * w3.z + S.hl[d + 15] * w3.w;
    }
    float a = ob[t] + ((p0 + p1) + (p2 + p3));
    S.xl[t] = a;
    p.u[((size_t)b * 4 + up) * CD + t] = a;
  }
  __syncthreads();
  {
    const float* wr = p.ugat_W + (size_t)t * CD;
    float p0 = 0.f, p1 = 0.f, p2 = 0.f, p3 = 0.f;
#pragma unroll 4
    for (int d = 0; d < CD; d += 16) {
      float4 w0 = *(const float4*)(wr + d);
      float4 w1 = *(const float4*)(wr + d + 4);
      float4 w2 = *(const float4*)(wr + d + 8);
      float4 w3 = *(const float4*)(wr + d + 12);
      p0 += S.xl[d +  0] * w0.x + S.xl[d +  1] * w0.y + S.xl[d +  2] * w0.z + S.xl[d +  3] * w0.w;
      p1 += S.xl[d +  4] * w1.x + S.xl[d +  5] * w1.y + S.xl[d +  6] * w1.z + S.xl[d +  7] * w1.w;
      p2 += S.xl[d +  8] * w2.x + S.xl[d +  9] * w2.y + S.xl[d + 10] * w2.z + S.xl[d + 11] * w2.w;
      p3 += S.xl[d + 12] * w3.x + S.xl[d + 13] * w3.y + S.xl[d + 14] * w3.z + S.xl[d + 15] * w3.w;
    }
    float a = (p0 + p1) + (p2 + p3);
    S.qkl[t] = a;
    p.uqk[((size_t)b * 4 + up) * CD + t] = a;
  }
  __syncthreads();
  if (t < 8) {
    const int h = t >> 1, which = t & 1;
    const float* w = p.ugat_att + h * 128 + which * 64;
    float s = 0.f;
    for (int j = 0; j < 64; j++) s += S.qkl[h * 64 + j] * w[j];
    p.sqk[(((size_t)b * 4 + up) * 4 + h) * 2 + which] = s;
  }
}

// ---------- R8-verified U_GAT attn + MLP + classifier block
__device__ __forceinline__ void mlp2_blk(const Params& p, int b, int trait, int t, char* smem)
{
  MlpS& S = *reinterpret_cast<MlpS*>(smem);
  for (int i = t; i < 4 * CD; i += 256) S.uq[i >> 8][i & 255] = p.uqk[(size_t)b * 4 * CD + i];
  if (t < 16) {
    int node = t >> 2, h = t & 3;
    S.sl[node][h] = p.sqk[(((size_t)b * 4 + node) * 4 + h) * 2 + 0];
    S.kl[node][h] = p.sqk[(((size_t)b * 4 + node) * 4 + h) * 2 + 1];
  }
  float ur = p.u[((size_t)b * 4 + trait) * CD + t];
  __syncthreads();
  {
    const int h = t >> 6;
    float e[4]; float ssum = 0.f;
#pragma unroll
    for (int k = 0; k < 4; k++) { e[k] = __expf(tanh_fast(S.sl[trait][h] + S.kl[k][h])); ssum += e[k]; }
    float hid = 0.f;
#pragma unroll
    for (int k = 0; k < 4; k++) hid += e[k] * S.uq[k][t];
    S.xl[t] = ur + tanh_fast(hid / ssum);
  }
  __syncthreads();
  if (t < CFH) {
    const float* r = p.mlp_w1 + (size_t)t * CD;
    float a = p.mlp_b1[t];
#pragma unroll 4
    for (int k = 0; k < CD; k += 4) {
      float4 v = *(const float4*)(r + k);
      a += S.xl[k] * v.x + S.xl[k + 1] * v.y + S.xl[k + 2] * v.z + S.xl[k + 3] * v.w;
    }
    S.h1[t] = fmaxf(a, 0.f);
  }
  __syncthreads();
  if (t < CFH) {
    const float* r = p.mlp_w2 + (size_t)t * CFH;
    float a = p.mlp_b2[t];
#pragma unroll 4
    for (int k = 0; k < CFH; k += 4) {
      float4 v = *(const float4*)(r + k);
      a += S.h1[k] * v.x + S.h1[k + 1] * v.y + S.h1[k + 2] * v.z + S.h1[k + 3] * v.w;
    }
    S.h2[t] = fmaxf(a, 0.f);
  }
  __syncthreads();
  if (t < CNC) {
    const float* fw = p.fcf[trait * 2];
    const float* fb = p.fcf[trait * 2 + 1];
    const float* r = fw + (size_t)t * CFH;
    float a = fb[t];
    for (int k = 0; k < CFH; k++) a += S.h2[k] * r[k];
    p.out[(size_t)trait * (CB * CNC) + b * CNC + t] = a;
  }
}

// ---------- cooperative mega-kernel v2: 512 blocks (2/CU, capacity-safe),
// explicit device fences around every grid.sync.
__global__ __launch_bounds__(256) void han_mega(Params p)
{
  cg::grid_group grid = cg::this_grid();
  __shared__ __align__(16) char smem[sizeof(AttnS)];
  const int bid = blockIdx.x;
  const int t   = threadIdx.x;
  __bf16* qk16 = (__bf16*)p.qk;

  // Phase A: gemm layer 1 (all 512) + aux serial in blocks 0..63
  gemm_tile(p.feature, p.pgat_W, p.pgat_att, qk16, p.sq, p.sk,
            bid & 3, bid >> 2, t, smem);
  if (bid < 64) {
    __syncthreads();
    up_q_aux(p, bid & 3, bid >> 2, t, smem);
  }
  __threadfence(); grid.sync(); __threadfence();

  // Phase B: attention layer 1 — 2 tiles per block
  {
    int tile = bid;
    attn_tile(qk16, p.sq, p.sk, p.pmask, p.feature, p.feat1, CN,
              tile & 7, (tile >> 3) & 7, tile >> 6, t, smem);
    __syncthreads();
    tile = bid + 512;
    attn_tile(qk16, p.sq, p.sk, p.pmask, p.feature, p.feat1, CN,
              tile & 7, (tile >> 3) & 7, tile >> 6, t, smem);
  }
  __threadfence(); grid.sync(); __threadfence();

  // Phase C: gemm layer 2 (all 512)
  gemm_tile(p.feat1, p.pgat_W, p.pgat_att, qk16, p.sq, p.sk,
            bid & 3, bid >> 2, t, smem);
  __threadfence(); grid.sync(); __threadfence();

  // Phase D: attention layer 2 -> comb (stride 513) — 2 tiles per block
  {
    int tile = bid;
    attn_tile(qk16, p.sq, p.sk, p.pmask, p.feat1, p.comb, CNP1,
              tile & 7, (tile >> 3) & 7, tile >> 6, t, smem);
    __syncthreads();
    tile = bid + 512;
    attn_tile(qk16, p.sq, p.sk, p.pmask, p.feat1, p.comb, CNP1,
              tile & 7, (tile >> 3) & 7, tile >> 6, t, smem);
  }
  __threadfence(); grid.sync(); __threadfence();

  // Phase E: UP_GAT head-sim (144 blocks)
  if (bid < 144) headsim_blk(p, bid / 9, (bid % 9) * 64, t, smem);
  __threadfence(); grid.sync(); __threadfence();

  // Phase F: up_out + ugat projection (64 blocks)
  if (bid < 64) out_ugat_blk(p, bid >> 2, bid & 3, t, smem);
  __threadfence(); grid.sync(); __threadfence();

  // Phase G: U_GAT attn + MLP + classifier (64 blocks)
  if (bid < 64) mlp2_blk(p, bid >> 2, bid & 3, t, smem);
}

// ========== R8-verified standalone kernels (fallback path) ==========

__global__ __launch_bounds__(256) void fb_gemm(Params p, const float* A, int withAux)
{
  __shared__ __align__(16) char smem[sizeof(GemmS) > sizeof(AuxS) ? sizeof(GemmS) : sizeof(AuxS)];
  const int t = threadIdx.x;
  __bf16* qk16 = (__bf16*)p.qk;
  if (blockIdx.y >= 128) {
    const int up = blockIdx.x, b = blockIdx.y - 128;
    up_q_aux(p, up, b, t, smem);
    return;
  }
  gemm_tile(A, p.pgat_W, p.pgat_att, qk16, p.sq, p.sk,
            blockIdx.x, blockIdx.y, t, smem);
  (void)withAux;
}

__global__ __launch_bounds__(256) void fb_attn(Params p, const float* fin, float* fout, int outStride)
{
  __shared__ __align__(16) char smem[sizeof(AttnS)];
  attn_tile((const __bf16*)p.qk, p.sq, p.sk, p.pmask, fin, fout, outStride,
            blockIdx.x, blockIdx.y, blockIdx.z, threadIdx.x, smem);
}

__global__ __launch_bounds__(256) void fb_headsim(Params p)
{
  __shared__ __align__(16) char smem[sizeof(HeadS)];
  headsim_blk(p, blockIdx.x, blockIdx.y * 64, threadIdx.x, smem);
}

__global__ __launch_bounds__(256) void fb_out_ugat(Params p)
{
  __shared__ __align__(16) char smem[sizeof(OutS)];
  out_ugat_blk(p, blockIdx.x, blockIdx.y, threadIdx.x, smem);
}

__global__ __launch_bounds__(256) void fb_mlp2(Params p)
{
  __shared__ __align__(16) char smem[sizeof(MlpS)];
  mlp2_blk(p, blockIdx.x, blockIdx.y, threadIdx.x, smem);
}

extern "C" void kernel_launch(void* const* d_in, const int* in_sizes, int n_in,
                              void* d_out, int out_size, void* d_ws, size_t ws_size,
                              hipStream_t stream) {
  (void)in_sizes; (void)n_in; (void)out_size; (void)ws_size;

  Params p;
  p.pmask    = (const float*)d_in[0];
  p.feature  = (const float*)d_in[1];
  p.cnode    = (const float*)d_in[2];
  p.pgat_W   = (const float*)d_in[3];
  p.pgat_att = (const float*)d_in[4];
  for (int i = 0; i < 4; i++)
    for (int j = 0; j < 6; j++) p.upw[i * 6 + j] = (const float*)d_in[5 + i * 6 + j];
  p.ugat_W   = (const float*)d_in[29];
  p.ugat_att = (const float*)d_in[30];
  p.mlp_w1 = (const float*)d_in[31];
  p.mlp_b1 = (const float*)d_in[32];
  p.mlp_w2 = (const float*)d_in[33];
  p.mlp_b2 = (const float*)d_in[34];
  for (int j = 0; j < 8; j++) p.fcf[j] = (const float*)d_in[35 + j];
  p.out = (float*)d_out;

  float* ws = (float*)d_ws;
  size_t o = 0;
  p.qk    = ws + o; o += (size_t)CB * CN * CD;    // bf16 storage
  p.feat1 = ws + o; o += (size_t)CB * CN * CD;
  p.comb  = ws + o; o += (size_t)CB * CNP1 * CD;
  p.sq    = ws + o; o += (size_t)CB * CPH * CN;
  p.sk    = ws + o; o += (size_t)CB * CPH * CN;
  p.qt    = ws + o; o += (size_t)4 * CB * CD;
  p.qkb   = ws + o; o += 4 * CB;
  p.den   = ws + o; o += CB * 4;
  p.head  = ws + o; o += (size_t)CB * 4 * CD;
  p.u     = ws + o; o += (size_t)CB * 4 * CD;
  p.uqk   = ws + o; o += (size_t)CB * 4 * CD;
  p.sqk   = ws + o; o += (size_t)CB * 4 * 4 * 2;
  p.weff  = ws + o; o += (size_t)4 * CD * CD;

  void* kargs[] = { &p };
  hipError_t err = hipLaunchCooperativeKernel((void*)han_mega, dim3(512), dim3(256),
                                              kargs, 0, stream);
  if (err != hipSuccess) {
    // fallback: R8-verified 7-launch pipeline (same math, regular launches)
    const float* A1 = p.feature;
    fb_gemm<<<dim3(4, 144), 256, 0, stream>>>(p, A1, 1);
    fb_attn<<<dim3(8, 8, CB), 256, 0, stream>>>(p, p.feature, p.feat1, CN);
    fb_gemm<<<dim3(4, 128), 256, 0, stream>>>(p, p.feat1, 0);
    fb_attn<<<dim3(8, 8, CB), 256, 0, stream>>>(p, p.feat1, p.comb, CNP1);
    fb_headsim<<<dim3(CB, 9), 256, 0, stream>>>(p);
    fb_out_ugat<<<dim3(CB, 4), 256, 0, stream>>>(p);
    fb_mlp2<<<dim3(CB, 4), 256, 0, stream>>>(p);
  }
}

// Round 12
// 259.935 us; speedup vs baseline: 4.2414x; 4.2414x over previous
//
#include <hip/hip_runtime.h>

constexpr int CB   = 16;    // batch
constexpr int CN   = 512;   // nodes
constexpr int CD   = 256;   // dim
constexpr int CPH  = 8;     // pgat heads
constexpr int CDH  = 32;    // CD / CPH
constexpr int CNP1 = 513;   // nodes + c_node
constexpr int CFH  = 128;
constexpr int CNC  = 2;

typedef __bf16 bf16x8 __attribute__((ext_vector_type(8)));
typedef __bf16 bf16x4 __attribute__((ext_vector_type(4)));
typedef float  f32x4  __attribute__((ext_vector_type(4)));

__device__ __forceinline__ float tanh_fast(float x) {
  x = fminf(fmaxf(x, -15.f), 15.f);
  float e = __expf(2.f * x);
  return (e - 1.f) / (e + 1.f);
}

__device__ __forceinline__ float exp2x_clamped(float x) {
  x = fminf(fmaxf(x, -18.f), 18.f);
  return __expf(2.f * x);
}

// ---------- bf16-split MFMA GEMM + fused sq/sk epilogue (R3-verified, staged).
// Launch 1 adds 64 aux blocks (blockIdx.y >= 128) doing the old up_q_all work
// (independent inputs/outputs -> rides in gemm1's shadow, saves a launch).
__global__ __launch_bounds__(256) void gemm_fused(
    const float* __restrict__ A, const float* __restrict__ W,
    const float* __restrict__ attnw, __bf16* __restrict__ C,
    float* __restrict__ sqT, float* __restrict__ skT,
    const float* __restrict__ cnode,
    const float* __restrict__ qw0, const float* __restrict__ qb0,
    const float* __restrict__ kw0, const float* __restrict__ kb0,
    const float* __restrict__ ow0,
    const float* __restrict__ qw1, const float* __restrict__ qb1,
    const float* __restrict__ kw1, const float* __restrict__ kb1,
    const float* __restrict__ ow1,
    const float* __restrict__ qw2, const float* __restrict__ qb2,
    const float* __restrict__ kw2, const float* __restrict__ kb2,
    const float* __restrict__ ow2,
    const float* __restrict__ qw3, const float* __restrict__ qb3,
    const float* __restrict__ kw3, const float* __restrict__ kb3,
    const float* __restrict__ ow3,
    float* __restrict__ qt_, float* __restrict__ qkb,
    float* __restrict__ comb, float* __restrict__ head, float* __restrict__ den,
    float* __restrict__ weff)
{
  const int t  = threadIdx.x;

  __shared__ __align__(16) __bf16 aHi[64][56];
  __shared__ __align__(16) __bf16 aLo[64][56];
  __shared__ __align__(16) __bf16 bHi[64][56];
  __shared__ __align__(16) __bf16 bLo[64][56];
  __shared__ float s_cl[CD];
  __shared__ float s_ql[CD];
  __shared__ float s_red[256];

  if (blockIdx.y >= 128) {
    const int up = blockIdx.x, b = blockIdx.y - 128;
    const float* qw = (up == 0) ? qw0 : (up == 1) ? qw1 : (up == 2) ? qw2 : qw3;
    const float* qb = (up == 0) ? qb0 : (up == 1) ? qb1 : (up == 2) ? qb2 : qb3;
    const float* kw = (up == 0) ? kw0 : (up == 1) ? kw1 : (up == 2) ? kw2 : kw3;
    const float* kb = (up == 0) ? kb0 : (up == 1) ? kb1 : (up == 2) ? kb2 : kb3;
    const float* ow = (up == 0) ? ow0 : (up == 1) ? ow1 : (up == 2) ? ow2 : ow3;
    s_cl[t] = cnode[b * CD + t];
    head[((size_t)b * 4 + up) * CD + t] = 0.f;
    if (t == 0) den[b * 4 + up] = 0.f;
    {
#pragma unroll
      for (int i = 0; i < 4; i++) {
        int idx = t + 256 * i;               // 0..1023
        int n = b * 16 + (idx >> 6), e4 = (idx & 63) * 4;
        const float* base = ow + (size_t)n * (4 * CD) + e4;
        float4 w0 = *(const float4*)(base);
        float4 w1 = *(const float4*)(base + CD);
        float4 w2 = *(const float4*)(base + 2 * CD);
        float4 w3 = *(const float4*)(base + 3 * CD);
        float4 o;
        o.x = w0.x + w1.x + w2.x + w3.x;
        o.y = w0.y + w1.y + w2.y + w3.y;
        o.z = w0.z + w1.z + w2.z + w3.z;
        o.w = w0.w + w1.w + w2.w + w3.w;
        *(float4*)(weff + (size_t)up * CD * CD + (size_t)n * CD + e4) = o;
      }
    }
    __syncthreads();
    if (up == 0) comb[((size_t)b * CNP1 + CN) * CD + t] = s_cl[t];
    {
      const float* wr = qw + (size_t)t * CD;
      float a = qb[t];
#pragma unroll 4
      for (int k = 0; k < CD; k += 4) {
        float4 w4 = *(const float4*)(wr + k);
        a += s_cl[k] * w4.x + s_cl[k + 1] * w4.y + s_cl[k + 2] * w4.z + s_cl[k + 3] * w4.w;
      }
      s_ql[t] = a;
    }
    __syncthreads();
    {
      float a0 = 0.f, a1 = 0.f, a2 = 0.f, a3 = 0.f;
#pragma unroll 4
      for (int d = 0; d < CD; d += 4) {
        a0 += s_ql[d]     * kw[(d)     * CD + t];
        a1 += s_ql[d + 1] * kw[(d + 1) * CD + t];
        a2 += s_ql[d + 2] * kw[(d + 2) * CD + t];
        a3 += s_ql[d + 3] * kw[(d + 3) * CD + t];
      }
      qt_[((size_t)up * CB + b) * CD + t] = (a0 + a1) + (a2 + a3);
    }
    s_red[t] = s_ql[t] * kb[t];
    __syncthreads();
    for (int s = 128; s > 0; s >>= 1) { if (t < s) s_red[t] += s_red[t + s]; __syncthreads(); }
    if (t == 0) qkb[up * CB + b] = s_red[0];
    return;
  }

  const int nt = blockIdx.x * 64;
  const int mt = blockIdx.y * 64;
  const int wv = t >> 6, ln = t & 63;
  const int quad = ln >> 4, lc = ln & 15;

  f32x4 acc[4];
#pragma unroll
  for (int j = 0; j < 4; j++)
#pragma unroll
    for (int r = 0; r < 4; r++) acc[j][r] = 0.f;

  const int sr  = t >> 2;
  const int skq = (t & 3) * 8;

  for (int k0 = 0; k0 < 256; k0 += 32) {
    __syncthreads();
    {
      const float* ap = A + (size_t)(mt + sr) * 256 + k0 + skq;
      const float* wp = W + (size_t)(nt + sr) * 256 + k0 + skq;
      float4 a0 = *(const float4*)ap, a1 = *(const float4*)(ap + 4);
      float4 w0 = *(const float4*)wp, w1 = *(const float4*)(wp + 4);
      float av[8] = {a0.x, a0.y, a0.z, a0.w, a1.x, a1.y, a1.z, a1.w};
      float wvv[8] = {w0.x, w0.y, w0.z, w0.w, w1.x, w1.y, w1.z, w1.w};
      bf16x8 ah, al, bh, bl;
#pragma unroll
      for (int j = 0; j < 8; j++) {
        ah[j] = (__bf16)av[j];
        al[j] = (__bf16)(av[j] - (float)ah[j]);
        bh[j] = (__bf16)wvv[j];
        bl[j] = (__bf16)(wvv[j] - (float)bh[j]);
      }
      *(bf16x8*)&aHi[sr][skq] = ah;
      *(bf16x8*)&aLo[sr][skq] = al;
      *(bf16x8*)&bHi[sr][skq] = bh;
      *(bf16x8*)&bLo[sr][skq] = bl;
    }
    __syncthreads();
    bf16x8 fah = *(const bf16x8*)&aHi[wv * 16 + lc][quad * 8];
    bf16x8 fal = *(const bf16x8*)&aLo[wv * 16 + lc][quad * 8];
#pragma unroll
    for (int j = 0; j < 4; j++) {
      bf16x8 fbh = *(const bf16x8*)&bHi[j * 16 + lc][quad * 8];
      bf16x8 fbl = *(const bf16x8*)&bLo[j * 16 + lc][quad * 8];
      acc[j] = __builtin_amdgcn_mfma_f32_16x16x32_bf16(fah, fbh, acc[j], 0, 0, 0);
      acc[j] = __builtin_amdgcn_mfma_f32_16x16x32_bf16(fah, fbl, acc[j], 0, 0, 0);
      acc[j] = __builtin_amdgcn_mfma_f32_16x16x32_bf16(fal, fbh, acc[j], 0, 0, 0);
    }
  }
#pragma unroll
  for (int j = 0; j < 4; j++)
#pragma unroll
    for (int r = 0; r < 4; r++)
      C[(size_t)(mt + wv * 16 + quad * 4 + r) * 256 + nt + j * 16 + lc] =
          (__bf16)acc[j][r];

  const int hA = blockIdx.x * 2, hB = hA + 1;
  const float wqa0 = attnw[hA * 64 + lc],      wqa1 = attnw[hA * 64 + 16 + lc];
  const float wka0 = attnw[hA * 64 + 32 + lc], wka1 = attnw[hA * 64 + 48 + lc];
  const float wqb0 = attnw[hB * 64 + lc],      wqb1 = attnw[hB * 64 + 16 + lc];
  const float wkb0 = attnw[hB * 64 + 32 + lc], wkb1 = attnw[hB * 64 + 48 + lc];
  float sqa[4], ska[4], sqb[4], skb[4];
#pragma unroll
  for (int r = 0; r < 4; r++) {
    sqa[r] = acc[0][r] * wqa0 + acc[1][r] * wqa1;
    ska[r] = acc[0][r] * wka0 + acc[1][r] * wka1;
    sqb[r] = acc[2][r] * wqb0 + acc[3][r] * wqb1;
    skb[r] = acc[2][r] * wkb0 + acc[3][r] * wkb1;
  }
#pragma unroll
  for (int m = 1; m <= 8; m <<= 1) {
#pragma unroll
    for (int r = 0; r < 4; r++) {
      sqa[r] += __shfl_xor(sqa[r], m);
      ska[r] += __shfl_xor(ska[r], m);
      sqb[r] += __shfl_xor(sqb[r], m);
      skb[r] += __shfl_xor(skb[r], m);
    }
  }
  if (lc == 0) {
#pragma unroll
    for (int r = 0; r < 4; r++) {
      int gm = mt + wv * 16 + quad * 4 + r;
      int bb = gm >> 9, nn = gm & 511;
      sqT[((size_t)bb * CPH + hA) * CN + nn] = sqa[r];
      skT[((size_t)bb * CPH + hA) * CN + nn] = ska[r];
      sqT[((size_t)bb * CPH + hB) * CN + nn] = sqb[r];
      skT[((size_t)bb * CPH + hB) * CN + nn] = skb[r];
    }
  }
}

// ---------- P_GAT attention (R3-verified).
// masks staged as 0/1; masked -> th=0 -> exp(0)=1 (bf16-identical to old path).
__global__ __launch_bounds__(256) void pgat_attn_mfma2(
    const __bf16* __restrict__ qk, const float* __restrict__ sqT,
    const float* __restrict__ skT, const float* __restrict__ pmask,
    const float* __restrict__ fin, float* __restrict__ fout, int outStride)
{
  const int qt = blockIdx.x;
  const int h  = blockIdx.y;
  const int b  = blockIdx.z;
  const int t  = threadIdx.x;
  const int wv = t >> 6;
  const int ln = t & 63;
  const int quad = ln >> 4;
  const int lc   = ln & 15;

  __shared__ __align__(16) __bf16 pbuf[128][72];
  __shared__ __align__(16) __bf16 vbuf[32][72];
  __shared__ float skl[CN];    // e^{2sk}
  __shared__ float ckm[CN];    // k mask as 0/1
  __shared__ float sql[128];   // e^{2sq}
  __shared__ float qfm[128];   // q mask as 0/1

  for (int i = t; i < CN; i += 256) {
    skl[i] = exp2x_clamped(skT[((size_t)b * CPH + h) * CN + i]);
    ckm[i] = (pmask[b * CN + i] == 0.f) ? 0.f : 1.f;
  }
  if (t < 128) {
    sql[t] = exp2x_clamped(sqT[((size_t)b * CPH + h) * CN + qt * 128 + t]);
    qfm[t] = (pmask[b * CN + qt * 128 + t] == 0.f) ? 0.f : 1.f;
  }

  f32x4 aV0 = {0.f,0.f,0.f,0.f}, aV1 = {0.f,0.f,0.f,0.f}, aD = {0.f,0.f,0.f,0.f};
  f32x4 bV0 = {0.f,0.f,0.f,0.f}, bV1 = {0.f,0.f,0.f,0.f}, bD = {0.f,0.f,0.f,0.f};
  bf16x8 ones;
#pragma unroll
  for (int j = 0; j < 8; j++) ones[j] = (__bf16)1.0f;

  const int qg  = t >> 1;
  const int kb  = (t & 1) * 32;
  const int vkk = t >> 3;
  const int vdq = (t & 7) * 4;

  for (int k0 = 0; k0 < CN; k0 += 64) {
    __syncthreads();
    {
      bf16x4 v0 = *(const bf16x4*)(qk + ((size_t)(b * CN + k0 + vkk)) * CD + h * CDH + vdq);
      bf16x4 v1 = *(const bf16x4*)(qk + ((size_t)(b * CN + k0 + 32 + vkk)) * CD + h * CDH + vdq);
      vbuf[vdq + 0][vkk] = v0[0]; vbuf[vdq + 1][vkk] = v0[1];
      vbuf[vdq + 2][vkk] = v0[2]; vbuf[vdq + 3][vkk] = v0[3];
      vbuf[vdq + 0][32 + vkk] = v1[0]; vbuf[vdq + 1][32 + vkk] = v1[1];
      vbuf[vdq + 2][32 + vkk] = v1[2]; vbuf[vdq + 3][32 + vkk] = v1[3];
    }
    {
      const float tq = sql[qg];
      const float qf = qfm[qg];
#pragma unroll
      for (int g = 0; g < 4; g++) {
        bf16x8 w;
#pragma unroll
        for (int j = 0; j < 8; j++) {
          const int kk = k0 + kb + g * 8 + j;
          float u  = tq * skl[kk];
          float th = (u - 1.f) * __builtin_amdgcn_rcpf(u + 1.f);
          th *= qf * ckm[kk];
          w[j] = (__bf16)__expf(th);
        }
        *(bf16x8*)&pbuf[qg][kb + g * 8] = w;
      }
    }
    __syncthreads();
#pragma unroll
    for (int s = 0; s < 2; s++) {
      bf16x8 b0 = *(const bf16x8*)&vbuf[lc][s * 32 + quad * 8];
      bf16x8 b1 = *(const bf16x8*)&vbuf[16 + lc][s * 32 + quad * 8];
      bf16x8 fa = *(const bf16x8*)&pbuf[wv * 16 + lc][s * 32 + quad * 8];
      bf16x8 fb = *(const bf16x8*)&pbuf[64 + wv * 16 + lc][s * 32 + quad * 8];
      aV0 = __builtin_amdgcn_mfma_f32_16x16x32_bf16(fa, b0, aV0, 0, 0, 0);
      aV1 = __builtin_amdgcn_mfma_f32_16x16x32_bf16(fa, b1, aV1, 0, 0, 0);
      aD  = __builtin_amdgcn_mfma_f32_16x16x32_bf16(fa, ones, aD, 0, 0, 0);
      bV0 = __builtin_amdgcn_mfma_f32_16x16x32_bf16(fb, b0, bV0, 0, 0, 0);
      bV1 = __builtin_amdgcn_mfma_f32_16x16x32_bf16(fb, b1, bV1, 0, 0, 0);
      bD  = __builtin_amdgcn_mfma_f32_16x16x32_bf16(fb, ones, bD, 0, 0, 0);
    }
  }
#pragma unroll
  for (int r = 0; r < 4; r++) {
    const int d0 = h * CDH + lc;
    {
      int q = qt * 128 + wv * 16 + quad * 4 + r;
      float inv = 1.f / aD[r];
      const float* ip = fin + ((size_t)b * CN + q) * CD;
      float*       op = fout + ((size_t)b * outStride + q) * CD;
      op[d0]      = ip[d0]      + tanh_fast(aV0[r] * inv);
      op[d0 + 16] = ip[d0 + 16] + tanh_fast(aV1[r] * inv);
    }
    {
      int q = qt * 128 + 64 + wv * 16 + quad * 4 + r;
      float inv = 1.f / bD[r];
      const float* ip = fin + ((size_t)b * CN + q) * CD;
      float*       op = fout + ((size_t)b * outStride + q) * CD;
      op[d0]      = ip[d0]      + tanh_fast(bV0[r] * inv);
      op[d0 + 16] = ip[d0 + 16] + tanh_fast(bV1[r] * inv);
    }
  }
}

// ========== UP_GAT stage ==========

// sim+exp+weighted-sum fused. grid (16, 9)
__global__ __launch_bounds__(256) void up_headsim(
    const float* __restrict__ comb, const float* __restrict__ qt,
    const float* __restrict__ qkb, const float* __restrict__ pmask,
    float* __restrict__ head, float* __restrict__ den)
{
  const int b = blockIdx.x, n0 = blockIdx.y * 64, t = threadIdx.x;
  const int up = t >> 6, j = t & 63;
  __shared__ float qtl[4][CD];
  __shared__ float qkbl[4];
  __shared__ float attl[4][64];
  for (int i = t; i < 4 * CD; i += 256)
    qtl[i >> 8][i & 255] = qt[((size_t)(i >> 8) * CB + b) * CD + (i & 255)];
  if (t < 4) qkbl[t] = qkb[t * CB + b];
  __syncthreads();
  {
    const int n = n0 + j;
    float e = 0.f;
    if (n < CNP1) {
      const float* cr = comb + ((size_t)b * CNP1 + n) * CD;
      float p = 0.f;
#pragma unroll 4
      for (int d = 0; d < CD; d += 4) {
        float4 c4 = *(const float4*)(cr + d);
        p += qtl[up][d] * c4.x + qtl[up][d + 1] * c4.y
           + qtl[up][d + 2] * c4.z + qtl[up][d + 3] * c4.w;
      }
      float s = (p + qkbl[up]) * 0.0625f;
      float m = (n < CN) ? pmask[b * CN + n] : 1.f;
      if (m == 0.f) s = 1e-8f;
      e = __expf(s);
    }
    attl[up][j] = e;
  }
  __syncthreads();
  float4 acc = make_float4(0.f, 0.f, 0.f, 0.f);
  const int nmax = min(64, CNP1 - n0);
  for (int jj = 0; jj < nmax; jj++) {
    float a = attl[up][jj];
    float4 c4 = *(const float4*)(comb + ((size_t)b * CNP1 + n0 + jj) * CD + j * 4);
    acc.x += a * c4.x; acc.y += a * c4.y; acc.z += a * c4.z; acc.w += a * c4.w;
  }
  float* hp = head + ((size_t)b * 4 + up) * CD + j * 4;
  atomicAdd(hp + 0, acc.x); atomicAdd(hp + 1, acc.y);
  atomicAdd(hp + 2, acc.z); atomicAdd(hp + 3, acc.w);
  if (j == 0) {
    float s = 0.f;
    for (int jj = 0; jj < 64; jj++) s += attl[up][jj];
    atomicAdd(den + b * 4 + up, s);
  }
}

// fused up_out + ugat projection, reading L2-resident weff. grid (16, 4).
__global__ __launch_bounds__(256) void up_out_ugat(
    const float* __restrict__ head, const float* __restrict__ den,
    const float* __restrict__ weff,
    const float* __restrict__ ob0, const float* __restrict__ ob1,
    const float* __restrict__ ob2, const float* __restrict__ ob3,
    const float* __restrict__ ugat_W, const float* __restrict__ attnw,
    float* __restrict__ uout, float* __restrict__ uqk, float* __restrict__ sqk)
{
  const int b = blockIdx.x, up = blockIdx.y, t = threadIdx.x;
  const float* ob = (up == 0) ? ob0 : (up == 1) ? ob1 : (up == 2) ? ob2 : ob3;
  __shared__ float hl[CD];
  __shared__ float xl[CD];
  __shared__ float qkl[CD];
  hl[t] = head[((size_t)b * 4 + up) * CD + t] * (1.f / den[b * 4 + up]);
  __syncthreads();
  {
    const float* r0 = weff + (size_t)up * CD * CD + (size_t)t * CD;
    float p0 = 0.f, p1 = 0.f, p2 = 0.f, p3 = 0.f;
#pragma unroll 4
    for (int d = 0; d < CD; d += 16) {
      float4 w0 = *(const float4*)(r0 + d);
      float4 w1 = *(const float4*)(r0 + d + 4);
      float4 w2 = *(const float4*)(r0 + d + 8);
      float4 w3 = *(const float4*)(r0 + d + 12);
      p0 += hl[d +  0] * w0.x + hl[d +  1] * w0.y + hl[d +  2] * w0.z + hl[d +  3] * w0.w;
      p1 += hl[d +  4] * w1.x + hl[d +  5] * w1.y + hl[d +  6] * w1.z + hl[d +  7] * w1.w;
      p2 += hl[d +  8] * w2.x + hl[d +  9] * w2.y + hl[d + 10] * w2.z + hl[d + 11] * w2.w;
      p3 += hl[d + 12] * w3.x + hl[d + 13] * w3.y + hl[d + 14] * w3.z + hl[d + 15] * w3.w;
    }
    float a = ob[t] + ((p0 + p1) + (p2 + p3));
    xl[t] = a;
    uout[((size_t)b * 4 + up) * CD + t] = a;
  }
  __syncthreads();
  {
    const float* wr = ugat_W + (size_t)t * CD;
    float p0 = 0.f, p1 = 0.f, p2 = 0.f, p3 = 0.f;
#pragma unroll 4
    for (int d = 0; d < CD; d += 16) {
      float4 w0 = *(const float4*)(wr + d);
      float4 w1 = *(const float4*)(wr + d + 4);
      float4 w2 = *(const float4*)(wr + d + 8);
      float4 w3 = *(const float4*)(wr + d + 12);
      p0 += xl[d +  0] * w0.x + xl[d +  1] * w0.y + xl[d +  2] * w0.z + xl[d +  3] * w0.w;
      p1 += xl[d +  4] * w1.x + xl[d +  5] * w1.y + xl[d +  6] * w1.z + xl[d +  7] * w1.w;
      p2 += xl[d +  8] * w2.x + xl[d +  9] * w2.y + xl[d + 10] * w2.z + xl[d + 11] * w2.w;
      p3 += xl[d + 12] * w3.x + xl[d + 13] * w3.y + xl[d + 14] * w3.z + xl[d + 15] * w3.w;
    }
    float a = (p0 + p1) + (p2 + p3);
    qkl[t] = a;
    uqk[((size_t)b * 4 + up) * CD + t] = a;
  }
  __syncthreads();
  if (t < 8) {
    const int h = t >> 1, which = t & 1;
    const float* w = attnw + h * 128 + which * 64;
    float s = 0.f;
    for (int j = 0; j < 64; j++) s += qkl[h * 64 + j] * w[j];
    sqk[(((size_t)b * 4 + up) * 4 + h) * 2 + which] = s;
  }
}

// fused U_GAT attention (per-trait) + MLP + classifier. grid (16,4).
__global__ __launch_bounds__(256) void ugat_mlp2(
    const float* __restrict__ u, const float* __restrict__ uqk,
    const float* __restrict__ sqk,
    const float* __restrict__ w1, const float* __restrict__ b1,
    const float* __restrict__ w2, const float* __restrict__ b2,
    const float* __restrict__ f1w, const float* __restrict__ f1b,
    const float* __restrict__ f2w, const float* __restrict__ f2b,
    const float* __restrict__ f3w, const float* __restrict__ f3b,
    const float* __restrict__ f4w, const float* __restrict__ f4b,
    float* __restrict__ out)
{
  const int b = blockIdx.x, trait = blockIdx.y, t = threadIdx.x;
  __shared__ float uq[4][CD];
  __shared__ float sl[4][4], kl[4][4];
  __shared__ float xl[CD];
  __shared__ float h1[CFH];
  __shared__ float h2[CFH];
  for (int i = t; i < 4 * CD; i += 256) uq[i >> 8][i & 255] = uqk[(size_t)b * 4 * CD + i];
  if (t < 16) {
    int node = t >> 2, h = t & 3;
    sl[node][h] = sqk[(((size_t)b * 4 + node) * 4 + h) * 2 + 0];
    kl[node][h] = sqk[(((size_t)b * 4 + node) * 4 + h) * 2 + 1];
  }
  float ur = u[((size_t)b * 4 + trait) * CD + t];
  __syncthreads();
  {
    const int h = t >> 6;
    float e[4]; float ssum = 0.f;
#pragma unroll
    for (int k = 0; k < 4; k++) { e[k] = __expf(tanh_fast(sl[trait][h] + kl[k][h])); ssum += e[k]; }
    float hid = 0.f;
#pragma unroll
    for (int k = 0; k < 4; k++) hid += e[k] * uq[k][t];
    xl[t] = ur + tanh_fast(hid / ssum);
  }
  __syncthreads();
  if (t < CFH) {
    const float* r = w1 + (size_t)t * CD;
    float a = b1[t];
#pragma unroll 4
    for (int k = 0; k < CD; k += 4) {
      float4 v = *(const float4*)(r + k);
      a += xl[k] * v.x + xl[k + 1] * v.y + xl[k + 2] * v.z + xl[k + 3] * v.w;
    }
    h1[t] = fmaxf(a, 0.f);
  }
  __syncthreads();
  if (t < CFH) {
    const float* r = w2 + (size_t)t * CFH;
    float a = b2[t];
#pragma unroll 4
    for (int k = 0; k < CFH; k += 4) {
      float4 v = *(const float4*)(r + k);
      a += h1[k] * v.x + h1[k + 1] * v.y + h1[k + 2] * v.z + h1[k + 3] * v.w;
    }
    h2[t] = fmaxf(a, 0.f);
  }
  __syncthreads();
  if (t < CNC) {
    const float* fw; const float* fb;
    switch (trait) {
      case 0:  fw = f1w; fb = f1b; break;
      case 1:  fw = f2w; fb = f2b; break;
      case 2:  fw = f3w; fb = f3b; break;
      default: fw = f4w; fb = f4b; break;
    }
    const float* r = fw + (size_t)t * CFH;
    float a = fb[t];
    for (int k = 0; k < CFH; k++) a += h2[k] * r[k];
    out[(size_t)trait * (CB * CNC) + b * CNC + t] = a;
  }
}

extern "C" void kernel_launch(void* const* d_in, const int* in_sizes, int n_in,
                              void* d_out, int out_size, void* d_ws, size_t ws_size,
                              hipStream_t stream) {
  (void)in_sizes; (void)n_in; (void)out_size; (void)ws_size;
  const float* pmask    = (const float*)d_in[0];
  const float* feature  = (const float*)d_in[1];
  const float* cnode    = (const float*)d_in[2];
  const float* pgat_W   = (const float*)d_in[3];
  const float* pgat_att = (const float*)d_in[4];
  const float* upw[4][6];
  for (int i = 0; i < 4; i++)
    for (int j = 0; j < 6; j++) upw[i][j] = (const float*)d_in[5 + i * 6 + j];
  const float* ugat_W   = (const float*)d_in[29];
  const float* ugat_att = (const float*)d_in[30];
  const float* mlp_w1 = (const float*)d_in[31];
  const float* mlp_b1 = (const float*)d_in[32];
  const float* mlp_w2 = (const float*)d_in[33];
  const float* mlp_b2 = (const float*)d_in[34];
  const float* fcf[8];
  for (int j = 0; j < 8; j++) fcf[j] = (const float*)d_in[35 + j];

  float* ws = (float*)d_ws;
  size_t o = 0;
  float* ws_qk   = ws + o; o += (size_t)CB * CN * CD;    // bf16 qk lives here
  float* ws_feat = ws + o; o += (size_t)CB * CN * CD;
  float* ws_comb = ws + o; o += (size_t)CB * CNP1 * CD;
  float* ws_sq   = ws + o; o += (size_t)CB * CPH * CN;
  float* ws_sk   = ws + o; o += (size_t)CB * CPH * CN;
  float* ws_qt   = ws + o; o += (size_t)4 * CB * CD;
  float* ws_qkb  = ws + o; o += 4 * CB;
  float* ws_den  = ws + o; o += CB * 4;
  float* ws_head = ws + o; o += (size_t)CB * 4 * CD;
  float* ws_u    = ws + o; o += (size_t)CB * 4 * CD;
  float* ws_uqk  = ws + o; o += (size_t)CB * 4 * CD;
  float* ws_sqk  = ws + o; o += (size_t)CB * 4 * 4 * 2;
  float* ws_weff = ws + o; o += (size_t)4 * CD * CD;
  __bf16* qk16 = (__bf16*)ws_qk;

  const dim3 gemmGrid1(CD / 64, (CB * CN) / 64 + 16);  // (4, 144): +64 aux blocks
  const dim3 gemmGrid2(CD / 64, (CB * CN) / 64);       // (4, 128)
  const dim3 attnGrid(CN / 128, CPH, CB);              // (4, 8, 16)

  // P_GAT layer 1 + (aux) up_q_all folded into the same launch
  gemm_fused<<<gemmGrid1, 256, 0, stream>>>(feature, pgat_W, pgat_att, qk16, ws_sq, ws_sk,
      cnode,
      upw[0][0], upw[0][1], upw[0][2], upw[0][3], upw[0][4],
      upw[1][0], upw[1][1], upw[1][2], upw[1][3], upw[1][4],
      upw[2][0], upw[2][1], upw[2][2], upw[2][3], upw[2][4],
      upw[3][0], upw[3][1], upw[3][2], upw[3][3], upw[3][4],
      ws_qt, ws_qkb, ws_comb, ws_head, ws_den, ws_weff);
  pgat_attn_mfma2<<<attnGrid, 256, 0, stream>>>(qk16, ws_sq, ws_sk, pmask, feature, ws_feat, CN);
  // P_GAT layer 2 (writes into comb rows, stride 513)
  gemm_fused<<<gemmGrid2, 256, 0, stream>>>(ws_feat, pgat_W, pgat_att, qk16, ws_sq, ws_sk,
      cnode,
      upw[0][0], upw[0][1], upw[0][2], upw[0][3], upw[0][4],
      upw[1][0], upw[1][1], upw[1][2], upw[1][3], upw[1][4],
      upw[2][0], upw[2][1], upw[2][2], upw[2][3], upw[2][4],
      upw[3][0], upw[3][1], upw[3][2], upw[3][3], upw[3][4],
      ws_qt, ws_qkb, ws_comb, ws_head, ws_den, ws_weff);
  pgat_attn_mfma2<<<attnGrid, 256, 0, stream>>>(qk16, ws_sq, ws_sk, pmask, ws_feat, ws_comb, CNP1);

  // UP_GAT head-sim (atomic accumulate into head/den)
  up_headsim<<<dim3(CB, (CNP1 + 63) / 64), 256, 0, stream>>>(ws_comb, ws_qt, ws_qkb, pmask,
                                                             ws_head, ws_den);
  up_out_ugat<<<dim3(CB, 4), 256, 0, stream>>>(ws_head, ws_den, ws_weff,
      upw[0][5], upw[1][5], upw[2][5], upw[3][5],
      ugat_W, ugat_att, ws_u, ws_uqk, ws_sqk);

  // U_GAT attention + MLP + heads
  ugat_mlp2<<<dim3(CB, 4), 256, 0, stream>>>(ws_u, ws_uqk, ws_sqk,
                                             mlp_w1, mlp_b1, mlp_w2, mlp_b2,
                                             fcf[0], fcf[1], fcf[2], fcf[3],
                                             fcf[4], fcf[5], fcf[6], fcf[7],
                                             (float*)d_out);
}